// Round 2
// baseline (15366.525 us; speedup 1.0000x reference)
//
#include <hip/hip_runtime.h>
#include <hip/hip_bf16.h>
#include <math.h>
#include <float.h>

typedef __hip_bfloat16 bf16;

constexpr int BATCH = 4;
constexpr int SEQ   = 2048;
constexpr int SEQ1  = 2049;
constexpr int DIN   = 768;
constexpr int DIMC  = 512;
constexpr int DEPTH = 2;
constexpr int NHEAD = 8;
constexpr int DHEAD = 64;
constexpr int MLPD  = 512;
constexpr int ROWS  = BATCH * SEQ1;   // 8196
constexpr float ATT_SCALE = 0.125f;   // 64^-0.5

// load external tensor element i, dtype chosen at runtime
__device__ __forceinline__ float ldext(const void* p, size_t i, bool f32) {
    return f32 ? ((const float*)p)[i] : __bfloat162float(((const bf16*)p)[i]);
}

// ---------------- dtype probe: bf16 N(0,1) data never has exp-field >= 0x90;
// fp32 data read as u16 has random exponents in the mantissa halves (~44% hit).
__global__ void probe_kernel(const void* __restrict__ x, int* __restrict__ flag) {
    __shared__ int red[256];
    int t = threadIdx.x;
    const unsigned short* u = (const unsigned short*)x;
    int cnt = 0;
    for (int i = t; i < 8192; i += 256) {
        int e = (u[i] >> 7) & 0xFF;
        cnt += (e >= 0x90) ? 1 : 0;
    }
    red[t] = cnt;
    __syncthreads();
    for (int w = 128; w > 0; w >>= 1) {
        if (t < w) red[t] += red[t + w];
        __syncthreads();
    }
    if (t == 0) *flag = (red[0] > 256) ? 1 : 0;   // 1 => fp32 world
}

// ---------------- cls token fill: X[b][0][:] = cls ----------------
__global__ void cls_fill_kernel(const void* __restrict__ cls, float* __restrict__ X,
                                const int* __restrict__ flag) {
    bool f32 = (*flag != 0);
    int b = blockIdx.x;
    for (int d = threadIdx.x; d < DIMC; d += blockDim.x)
        X[(size_t)b * SEQ1 * DIMC + d] = ldext(cls, d, f32);
}

// ---------------- generic tiled GEMM: C[M,Nn] = A[M,K] @ Bw[K,Nn] (+bias)(gelu)(+resid) ----------------
// 64x64 tile, BK=16, 256 threads, 4x4 microtile per thread.
// AEXT: A is an external tensor (dtype by flag); else A is fp32 workspace.
template<bool AEXT, bool GELU_, bool RESID, bool REMAP>
__global__ void gemm_kernel(const void* __restrict__ A,
                            const void* __restrict__ Bw, long woff,
                            const void* __restrict__ bias, long boff,
                            const float* __restrict__ resid,
                            float* __restrict__ C, int M, int Nn, int K,
                            const int* __restrict__ flag) {
    bool f32 = (*flag != 0);
    __shared__ float As[16][65];
    __shared__ float Bs[16][65];
    int tid = threadIdx.x;
    int tx = tid & 15, ty = tid >> 4;
    int m0 = blockIdx.y * 64, n0 = blockIdx.x * 64;

    float acc[4][4];
#pragma unroll
    for (int i = 0; i < 4; ++i)
#pragma unroll
        for (int j = 0; j < 4; ++j) acc[i][j] = 0.f;

    for (int k0 = 0; k0 < K; k0 += 16) {
#pragma unroll
        for (int idx = tid; idx < 64 * 16; idx += 256) {
            int m = idx >> 4, k = idx & 15;
            int gm = m0 + m;
            float v = 0.f;
            if (gm < M) {
                size_t ai = (size_t)gm * K + (k0 + k);
                v = AEXT ? ldext(A, ai, f32) : ((const float*)A)[ai];
            }
            As[k][m] = v;
        }
#pragma unroll
        for (int idx = tid; idx < 16 * 64; idx += 256) {
            int k = idx >> 6, n = idx & 63;
            Bs[k][n] = ldext(Bw, (size_t)woff + (size_t)(k0 + k) * Nn + (n0 + n), f32);
        }
        __syncthreads();
#pragma unroll
        for (int kk = 0; kk < 16; ++kk) {
            float a[4], bv[4];
#pragma unroll
            for (int i = 0; i < 4; ++i) a[i] = As[kk][ty + i * 16];
#pragma unroll
            for (int j = 0; j < 4; ++j) bv[j] = Bs[kk][tx + j * 16];
#pragma unroll
            for (int i = 0; i < 4; ++i)
#pragma unroll
                for (int j = 0; j < 4; ++j) acc[i][j] += a[i] * bv[j];
        }
        __syncthreads();
    }

#pragma unroll
    for (int i = 0; i < 4; ++i) {
        int gm = m0 + ty + i * 16;
        if (gm >= M) continue;
        size_t orow = gm;
        if (REMAP) {  // fc output: row (b*2048+i) -> X row b*2049 + i + 1
            int bb = gm >> 11;
            orow = (size_t)bb * SEQ1 + (gm & 2047) + 1;
        }
#pragma unroll
        for (int j = 0; j < 4; ++j) {
            int gn = n0 + tx + j * 16;
            float v = acc[i][j];
            if (bias) v += ldext(bias, (size_t)boff + gn, f32);
            if (GELU_) v = 0.5f * v * (1.f + erff(v * 0.70710678118654752f));
            size_t oi = orow * (size_t)Nn + gn;
            if (RESID) v += resid[oi];
            C[oi] = v;
        }
    }
}

// ---------------- LayerNorm: per row over DIMC=512, 256 threads ----------------
__global__ void ln_kernel(const float* __restrict__ Xin, float* __restrict__ Xout,
                          const void* __restrict__ g, const void* __restrict__ bb,
                          long off, const int* __restrict__ flag) {
    bool f32 = (*flag != 0);
    int row = blockIdx.x;
    int t = threadIdx.x;
    const float* xr = Xin + (size_t)row * DIMC;
    float v0 = xr[t], v1 = xr[t + 256];
    __shared__ float red[256];
    red[t] = v0 + v1;
    __syncthreads();
    for (int w = 128; w > 0; w >>= 1) {
        if (t < w) red[t] += red[t + w];
        __syncthreads();
    }
    float mean = red[0] * (1.f / 512.f);
    __syncthreads();
    float d0 = v0 - mean, d1 = v1 - mean;
    red[t] = d0 * d0 + d1 * d1;
    __syncthreads();
    for (int w = 128; w > 0; w >>= 1) {
        if (t < w) red[t] += red[t + w];
        __syncthreads();
    }
    float rinv = rsqrtf(red[0] * (1.f / 512.f) + 1e-5f);
    float* orow = Xout + (size_t)row * DIMC;
    orow[t]       = d0 * rinv * ldext(g, off + t, f32)       + ldext(bb, off + t, f32);
    orow[t + 256] = d1 * rinv * ldext(g, off + t + 256, f32) + ldext(bb, off + t + 256, f32);
}

// ---------------- attention: one block per (query, head, batch) ----------------
// mask2[q,j] = (q >= len1) && (j >= len1)  -> -FLT_MAX (matches pad & pad.mT)
__global__ void attn_kernel(const float* __restrict__ QKV, const int* __restrict__ lens,
                            float* __restrict__ O) {
    int q = blockIdx.x, h = blockIdx.y, b = blockIdx.z;
    int t = threadIdx.x;
    const float* qkvb = QKV + (size_t)b * SEQ1 * 1536;

    __shared__ __align__(16) float qs[DHEAD];
    __shared__ float s[SEQ1];
    __shared__ float red[256];
    __shared__ float ored[4][DHEAD];

    if (t < DHEAD) qs[t] = qkvb[(size_t)q * 1536 + h * DHEAD + t];
    __syncthreads();

    int len1 = lens[b] + 1;
    bool qpad = (q >= len1);

    for (int j = t; j < SEQ1; j += 256) {
        const float4* k4 = (const float4*)(qkvb + (size_t)j * 1536 + 512 + h * DHEAD);
        const float4* q4 = (const float4*)qs;
        float acc = 0.f;
#pragma unroll
        for (int d = 0; d < 16; ++d) {
            float4 kv = k4[d], qv = q4[d];
            acc += qv.x * kv.x + qv.y * kv.y + qv.z * kv.z + qv.w * kv.w;
        }
        s[j] = (qpad && j >= len1) ? -FLT_MAX : acc * ATT_SCALE;
    }
    __syncthreads();

    float lm = -FLT_MAX;
    for (int j = t; j < SEQ1; j += 256) lm = fmaxf(lm, s[j]);
    red[t] = lm;
    __syncthreads();
    for (int w = 128; w > 0; w >>= 1) {
        if (t < w) red[t] = fmaxf(red[t], red[t + w]);
        __syncthreads();
    }
    float m = red[0];
    __syncthreads();

    float ls = 0.f;
    for (int j = t; j < SEQ1; j += 256) {
        float p = expf(s[j] - m);
        s[j] = p;
        ls += p;
    }
    red[t] = ls;
    __syncthreads();
    for (int w = 128; w > 0; w >>= 1) {
        if (t < w) red[t] += red[t + w];
        __syncthreads();
    }
    float l = red[0];
    __syncthreads();

    int d = t & 63, g = t >> 6;
    float acc = 0.f;
    for (int j = g; j < SEQ1; j += 4)
        acc += s[j] * qkvb[(size_t)j * 1536 + 1024 + h * DHEAD + d];
    ored[g][d] = acc;
    __syncthreads();
    if (t < DHEAD) {
        float o = (ored[0][t] + ored[1][t] + ored[2][t] + ored[3][t]) / l;
        O[((size_t)b * SEQ1 + q) * DIMC + h * DHEAD + t] = o;
    }
}

// ---------------- head: out[b,c] = XN[b,0,:] @ head_w[:,c] + head_b[c] ----------------
__global__ void head_kernel(const float* __restrict__ XN, const void* __restrict__ hw,
                            const void* __restrict__ hb, void* __restrict__ outv,
                            const int* __restrict__ flag) {
    bool f32 = (*flag != 0);
    int b = blockIdx.x, t = threadIdx.x;
    const float* xr = XN + (size_t)b * SEQ1 * DIMC;
    float p0 = 0.f, p1 = 0.f;
    for (int d = t; d < DIMC; d += 256) {
        float v = xr[d];
        p0 += v * ldext(hw, (size_t)d * 2, f32);
        p1 += v * ldext(hw, (size_t)d * 2 + 1, f32);
    }
    __shared__ float r0[256], r1[256];
    r0[t] = p0; r1[t] = p1;
    __syncthreads();
    for (int w = 128; w > 0; w >>= 1) {
        if (t < w) { r0[t] += r0[t + w]; r1[t] += r1[t + w]; }
        __syncthreads();
    }
    if (t == 0) {
        float o0 = r0[0] + ldext(hb, 0, f32);
        float o1 = r1[0] + ldext(hb, 1, f32);
        if (f32) {
            ((float*)outv)[b * 2 + 0] = o0;
            ((float*)outv)[b * 2 + 1] = o1;
        } else {
            ((bf16*)outv)[b * 2 + 0] = __float2bfloat16(o0);
            ((bf16*)outv)[b * 2 + 1] = __float2bfloat16(o1);
        }
    }
}

extern "C" void kernel_launch(void* const* d_in, const int* in_sizes, int n_in,
                              void* d_out, int out_size, void* d_ws, size_t ws_size,
                              hipStream_t stream) {
    const void* x      = d_in[0];
    const int*  lens   = (const int*)d_in[1];
    const void* cls    = d_in[2];
    const void* fc_w   = d_in[3];
    const void* fc_b   = d_in[4];
    const void* ln1_g  = d_in[5];
    const void* ln1_b  = d_in[6];
    const void* qkv_w  = d_in[7];
    const void* out_w  = d_in[8];
    const void* out_b  = d_in[9];
    const void* ln2_g  = d_in[10];
    const void* ln2_b  = d_in[11];
    const void* ff1_w  = d_in[12];
    const void* ff1_b  = d_in[13];
    const void* ff2_w  = d_in[14];
    const void* ff2_b  = d_in[15];
    const void* lnf_g  = d_in[16];
    const void* lnf_b  = d_in[17];
    const void* head_w = d_in[18];
    const void* head_b = d_in[19];

    // workspace (fp32): X | XN (aliased by Ob) | QKV (aliased by Hb) | flag
    float* X   = (float*)d_ws;                      // [ROWS, 512]
    float* XN  = X   + (size_t)ROWS * DIMC;         // [ROWS, 512]
    float* QKV = XN  + (size_t)ROWS * DIMC;         // [ROWS, 1536]
    float* Ob  = XN;                                // alias: XN dead after qkv gemm
    float* Hb  = QKV;                               // alias: QKV dead after attention
    int* flag  = (int*)(QKV + (size_t)ROWS * 1536);

    dim3 blk(256);

    probe_kernel<<<dim3(1), blk, 0, stream>>>(x, flag);

    {   // fc + gelu, remapped into X rows (cls slot left for cls_fill)
        dim3 grid(DIMC / 64, (BATCH * SEQ + 63) / 64);
        gemm_kernel<true, true, false, true><<<grid, blk, 0, stream>>>(
            x, fc_w, 0, fc_b, 0, nullptr, X, BATCH * SEQ, DIMC, DIN, flag);
    }
    cls_fill_kernel<<<dim3(BATCH), blk, 0, stream>>>(cls, X, flag);

    for (int l = 0; l < DEPTH; ++l) {
        ln_kernel<<<dim3(ROWS), blk, 0, stream>>>(X, XN, ln1_g, ln1_b, (long)l * DIMC, flag);
        {
            dim3 grid(1536 / 64, (ROWS + 63) / 64);
            gemm_kernel<false, false, false, false><<<grid, blk, 0, stream>>>(
                XN, qkv_w, (long)l * DIMC * 1536, nullptr, 0, nullptr, QKV, ROWS, 1536, DIMC, flag);
        }
        attn_kernel<<<dim3(SEQ1, NHEAD, BATCH), blk, 0, stream>>>(QKV, lens, Ob);
        {
            dim3 grid(DIMC / 64, (ROWS + 63) / 64);
            gemm_kernel<false, false, true, false><<<grid, blk, 0, stream>>>(
                Ob, out_w, (long)l * DIMC * DIMC, out_b, (long)l * DIMC, X, X, ROWS, DIMC, DIMC, flag);
        }
        ln_kernel<<<dim3(ROWS), blk, 0, stream>>>(X, XN, ln2_g, ln2_b, (long)l * DIMC, flag);
        {
            dim3 grid(MLPD / 64, (ROWS + 63) / 64);
            gemm_kernel<false, true, false, false><<<grid, blk, 0, stream>>>(
                XN, ff1_w, (long)l * DIMC * MLPD, ff1_b, (long)l * MLPD, nullptr, Hb, ROWS, MLPD, DIMC, flag);
        }
        {
            dim3 grid(DIMC / 64, (ROWS + 63) / 64);
            gemm_kernel<false, false, true, false><<<grid, blk, 0, stream>>>(
                Hb, ff2_w, (long)l * MLPD * DIMC, ff2_b, (long)l * DIMC, X, X, ROWS, DIMC, MLPD, flag);
        }
    }
    ln_kernel<<<dim3(ROWS), blk, 0, stream>>>(X, XN, lnf_g, lnf_b, 0, flag);
    head_kernel<<<dim3(BATCH), blk, 0, stream>>>(XN, head_w, head_b, d_out, flag);
}

// Round 6
// 8643.813 us; speedup vs baseline: 1.7777x; 1.7777x over previous
//
#include <hip/hip_runtime.h>
#include <hip/hip_bf16.h>
#include <math.h>
#include <float.h>

typedef __hip_bfloat16 bf16;
using bf16x8 = __attribute__((ext_vector_type(8))) __bf16;
using f32x4  = __attribute__((ext_vector_type(4))) float;

constexpr int BATCH = 4;
constexpr int SEQ   = 2048;
constexpr int SEQ1  = 2049;
constexpr int DIN   = 768;
constexpr int DIMC  = 512;
constexpr int DEPTH = 2;
constexpr int NHEAD = 8;
constexpr int DHEAD = 64;
constexpr int ROWS  = BATCH * SEQ1;   // 8196
constexpr float ATT_SCALE = 0.125f;
constexpr float NEGBIG = -1e30f;

__device__ __forceinline__ float ldh(const bf16* p) { return __bfloat162float(*p); }
__device__ __forceinline__ bf16x8 ld_frag(const bf16* p) { return *(const bf16x8*)p; }

// ---------------- cast fp32 -> bf16 (x stem input) ----------------
__global__ __launch_bounds__(256) void cast_kernel(const float* __restrict__ src,
                                                   bf16* __restrict__ dst, int n4) {
    int i = blockIdx.x * 256 + threadIdx.x;
    if (i < n4) {
        float4 v = ((const float4*)src)[i];
        dst[i * 4 + 0] = __float2bfloat16(v.x);
        dst[i * 4 + 1] = __float2bfloat16(v.y);
        dst[i * 4 + 2] = __float2bfloat16(v.z);
        dst[i * 4 + 3] = __float2bfloat16(v.w);
    }
}

// ---------------- transpose + cast: src[R][C] fp32 -> dst[C][R] bf16, z batches ----------------
__global__ __launch_bounds__(256) void transpose_kernel(
    const float* __restrict__ src, bf16* __restrict__ dst,
    int R, int C, long zstride) {
    __shared__ bf16 tile[32][33];
    int z = blockIdx.z;
    const float* s = src + (size_t)z * zstride;
    bf16* d = dst + (size_t)z * zstride;
    int tx = threadIdx.x, ty = threadIdx.y;
    int c0 = blockIdx.x * 32, r0 = blockIdx.y * 32;
    int c = c0 + tx;
#pragma unroll
    for (int rr = ty; rr < 32; rr += 8) {
        int r = r0 + rr;
        tile[rr][tx] = (r < R && c < C) ? __float2bfloat16(s[(size_t)r * C + c])
                                        : __float2bfloat16(0.f);
    }
    __syncthreads();
    int rc = r0 + tx;
#pragma unroll
    for (int cc = ty; cc < 32; cc += 8) {
        int oc = c0 + cc;
        if (rc < R && oc < C) d[(size_t)oc * R + rc] = tile[tx][cc];
    }
}

// ---------------- cls fill (fp32 in, fp32 X) ----------------
__global__ void cls_fill_kernel(const float* __restrict__ cls, float* __restrict__ X) {
    int b = blockIdx.x;
    for (int d = threadIdx.x; d < DIMC; d += blockDim.x)
        X[(size_t)b * SEQ1 * DIMC + d] = cls[d];
}

// ---------------- MFMA GEMM: C[M,N] = A[M,K](bf16) @ Bt[N,K]^T (+bias fp32)(gelu)(+resid fp32) ----------------
// 128x128 tile, BK=32, 256 threads / 4 waves, wave computes 4x4 grid of 16x16 mfma tiles.
template<bool GELU_, bool RESID, bool REMAP, bool OBF>
__global__ __launch_bounds__(256) void gemm_bt(
    const bf16* __restrict__ A, const bf16* __restrict__ Bt,
    const float* __restrict__ bias, const float* __restrict__ resid,
    float* __restrict__ Cf, bf16* __restrict__ Ch, int M, int N, int K) {
    __shared__ __align__(16) bf16 As[4096];
    __shared__ __align__(16) bf16 Bs[4096];
    int tid = threadIdx.x;
    int ln = tid & 63, wv = tid >> 6;
    int wr = wv >> 1, wc = wv & 1;
    int l15 = ln & 15, l4 = ln >> 4;
    int m0 = blockIdx.y * 128, n0 = blockIdx.x * 128;

    f32x4 acc[4][4];
#pragma unroll
    for (int i = 0; i < 4; ++i)
#pragma unroll
        for (int j = 0; j < 4; ++j) acc[i][j] = {0.f, 0.f, 0.f, 0.f};

    int aslot[4], bslot[4];
#pragma unroll
    for (int i = 0; i < 4; ++i) {
        int m = wr * 64 + i * 16 + l15;
        aslot[i] = m * 4 + (l4 ^ ((m >> 1) & 3));
        int n = wc * 64 + i * 16 + l15;
        bslot[i] = n * 4 + (l4 ^ ((n >> 1) & 3));
    }

    for (int k0 = 0; k0 < K; k0 += 32) {
#pragma unroll
        for (int r = 0; r < 2; ++r) {
            int s = r * 256 + tid;
            int m = s >> 2, c = s & 3;
            int kb = c ^ ((m >> 1) & 3);
            int gm = m0 + m; if (gm > M - 1) gm = M - 1;   // clamp; results discarded at store
            uint4 v = *(const uint4*)(A + (size_t)gm * K + k0 + kb * 8);
            *(uint4*)&As[s * 8] = v;
        }
#pragma unroll
        for (int r = 0; r < 2; ++r) {
            int s = r * 256 + tid;
            int n = s >> 2, c = s & 3;
            int kb = c ^ ((n >> 1) & 3);
            uint4 v = *(const uint4*)(Bt + (size_t)(n0 + n) * K + k0 + kb * 8);
            *(uint4*)&Bs[s * 8] = v;
        }
        __syncthreads();
        bf16x8 af[4], bfr[4];
#pragma unroll
        for (int i = 0; i < 4; ++i) af[i] = ld_frag(&As[aslot[i] * 8]);
#pragma unroll
        for (int j = 0; j < 4; ++j) bfr[j] = ld_frag(&Bs[bslot[j] * 8]);
#pragma unroll
        for (int i = 0; i < 4; ++i)
#pragma unroll
            for (int j = 0; j < 4; ++j)
                acc[i][j] = __builtin_amdgcn_mfma_f32_16x16x32_bf16(af[i], bfr[j], acc[i][j], 0, 0, 0);
        __syncthreads();
    }

#pragma unroll
    for (int i = 0; i < 4; ++i) {
#pragma unroll
        for (int j = 0; j < 4; ++j) {
            int gn = n0 + wc * 64 + j * 16 + l15;
            float bb = bias ? bias[gn] : 0.f;
#pragma unroll
            for (int r = 0; r < 4; ++r) {
                int gm = m0 + wr * 64 + i * 16 + l4 * 4 + r;
                if (gm >= M) continue;
                float v = acc[i][j][r] + bb;
                if (GELU_) v = 0.5f * v * (1.f + erff(v * 0.70710678118654752f));
                size_t orow = gm;
                if (REMAP) { int b_ = gm >> 11; orow = (size_t)b_ * SEQ1 + (gm & 2047) + 1; }
                size_t oi = orow * (size_t)N + gn;
                if (RESID) v += resid[oi];
                if (OBF) Ch[oi] = __float2bfloat16(v); else Cf[oi] = v;
            }
        }
    }
}

// ---------------- LayerNorm: X fp32 -> XN bf16 (g,b fp32) ----------------
__global__ __launch_bounds__(256) void ln_kernel(const float* __restrict__ Xin, bf16* __restrict__ Xout,
                          const float* __restrict__ g, const float* __restrict__ bb) {
    int row = blockIdx.x;
    int t = threadIdx.x;
    const float* xr = Xin + (size_t)row * DIMC;
    float v0 = xr[t], v1 = xr[t + 256];
    __shared__ float red[256];
    red[t] = v0 + v1;
    __syncthreads();
    for (int w = 128; w > 0; w >>= 1) { if (t < w) red[t] += red[t + w]; __syncthreads(); }
    float mean = red[0] * (1.f / 512.f);
    __syncthreads();
    float d0 = v0 - mean, d1 = v1 - mean;
    red[t] = d0 * d0 + d1 * d1;
    __syncthreads();
    for (int w = 128; w > 0; w >>= 1) { if (t < w) red[t] += red[t + w]; __syncthreads(); }
    float rinv = rsqrtf(red[0] * (1.f / 512.f) + 1e-5f);
    bf16* orow = Xout + (size_t)row * DIMC;
    orow[t]       = __float2bfloat16(d0 * rinv * g[t]       + bb[t]);
    orow[t + 256] = __float2bfloat16(d1 * rinv * g[t + 256] + bb[t + 256]);
}

// ---------------- attention (round-2-proven algorithm, bf16 QKV in / bf16 O out) ----------------
__global__ __launch_bounds__(256) void attn2_kernel(const bf16* __restrict__ QKV,
                                                    const int* __restrict__ lens,
                                                    bf16* __restrict__ O) {
    int q = blockIdx.x, h = blockIdx.y, b = blockIdx.z;
    int t = threadIdx.x;
    const bf16* qkv_b = QKV + (size_t)b * SEQ1 * 1536;

    __shared__ float qs[DHEAD];
    __shared__ float s[SEQ1];
    __shared__ float red[256];
    __shared__ float ored[4][DHEAD];

    if (t < DHEAD) qs[t] = ldh(qkv_b + (size_t)q * 1536 + h * DHEAD + t);
    __syncthreads();

    int len1 = lens[b] + 1;
    bool qpad = (q >= len1);

    for (int j = t; j < SEQ1; j += 256) {
        const uint4* kp = (const uint4*)(qkv_b + (size_t)j * 1536 + 512 + h * DHEAD);
        float acc = 0.f;
#pragma unroll
        for (int c = 0; c < 4; ++c) {
            uint4 kv = kp[c];
            unsigned u[4] = {kv.x, kv.y, kv.z, kv.w};
#pragma unroll
            for (int w = 0; w < 4; ++w) {
                acc += qs[c * 8 + 2 * w]     * __uint_as_float(u[w] << 16);
                acc += qs[c * 8 + 2 * w + 1] * __uint_as_float(u[w] & 0xFFFF0000u);
            }
        }
        s[j] = (qpad && j >= len1) ? NEGBIG : acc * ATT_SCALE;
    }
    __syncthreads();

    float lm = NEGBIG;
    for (int j = t; j < SEQ1; j += 256) lm = fmaxf(lm, s[j]);
    red[t] = lm;
    __syncthreads();
    for (int w = 128; w > 0; w >>= 1) { if (t < w) red[t] = fmaxf(red[t], red[t + w]); __syncthreads(); }
    float m = red[0];
    __syncthreads();

    float ls = 0.f;
    for (int j = t; j < SEQ1; j += 256) {
        float ex = s[j] - m;
        float p = (ex < -80.f) ? 0.f : __expf(ex);
        s[j] = p;
        ls += p;
    }
    red[t] = ls;
    __syncthreads();
    for (int w = 128; w > 0; w >>= 1) { if (t < w) red[t] += red[t + w]; __syncthreads(); }
    float l = red[0];
    __syncthreads();

    int d = t & 63, g = t >> 6;
    float acc = 0.f;
    for (int j = g; j < SEQ1; j += 4)
        acc += s[j] * ldh(qkv_b + (size_t)j * 1536 + 1024 + h * DHEAD + d);
    ored[g][d] = acc;
    __syncthreads();
    if (t < DHEAD) {
        float o = (ored[0][t] + ored[1][t] + ored[2][t] + ored[3][t]) / l;
        O[((size_t)b * SEQ1 + q) * DIMC + h * DHEAD + t] = __float2bfloat16(o);
    }
}

// ---------------- fused final LN + head (cls row only), all fp32 ----------------
__global__ __launch_bounds__(256) void head_kernel(const float* __restrict__ X,
                            const float* __restrict__ g, const float* __restrict__ bb,
                            const float* __restrict__ hw, const float* __restrict__ hb,
                            float* __restrict__ out) {
    int b = blockIdx.x, t = threadIdx.x;
    const float* xr = X + (size_t)b * SEQ1 * DIMC;
    float v0 = xr[t], v1 = xr[t + 256];
    __shared__ float red[256];
    red[t] = v0 + v1;
    __syncthreads();
    for (int w = 128; w > 0; w >>= 1) { if (t < w) red[t] += red[t + w]; __syncthreads(); }
    float mean = red[0] * (1.f / 512.f);
    __syncthreads();
    float d0 = v0 - mean, d1 = v1 - mean;
    red[t] = d0 * d0 + d1 * d1;
    __syncthreads();
    for (int w = 128; w > 0; w >>= 1) { if (t < w) red[t] += red[t + w]; __syncthreads(); }
    float rinv = rsqrtf(red[0] * (1.f / 512.f) + 1e-5f);
    __syncthreads();
    float xn0 = d0 * rinv * g[t] + bb[t];
    float xn1 = d1 * rinv * g[t + 256] + bb[t + 256];
    float p0 = xn0 * hw[t * 2]     + xn1 * hw[(t + 256) * 2];
    float p1 = xn0 * hw[t * 2 + 1] + xn1 * hw[(t + 256) * 2 + 1];
    __shared__ float r0[256], r1[256];
    r0[t] = p0; r1[t] = p1;
    __syncthreads();
    for (int w = 128; w > 0; w >>= 1) { if (t < w) { r0[t] += r0[t + w]; r1[t] += r1[t + w]; } __syncthreads(); }
    if (t == 0) {
        out[b * 2 + 0] = r0[0] + hb[0];
        out[b * 2 + 1] = r1[0] + hb[1];
    }
}

extern "C" void kernel_launch(void* const* d_in, const int* in_sizes, int n_in,
                              void* d_out, int out_size, void* d_ws, size_t ws_size,
                              hipStream_t stream) {
    const float* x      = (const float*)d_in[0];
    const int*   lens   = (const int*)d_in[1];
    const float* cls    = (const float*)d_in[2];
    const float* fc_w   = (const float*)d_in[3];
    const float* fc_b   = (const float*)d_in[4];
    const float* ln1_g  = (const float*)d_in[5];
    const float* ln1_b  = (const float*)d_in[6];
    const float* qkv_w  = (const float*)d_in[7];
    const float* out_w  = (const float*)d_in[8];
    const float* out_b  = (const float*)d_in[9];
    const float* ln2_g  = (const float*)d_in[10];
    const float* ln2_b  = (const float*)d_in[11];
    const float* ff1_w  = (const float*)d_in[12];
    const float* ff1_b  = (const float*)d_in[13];
    const float* ff2_w  = (const float*)d_in[14];
    const float* ff2_b  = (const float*)d_in[15];
    const float* lnf_g  = (const float*)d_in[16];
    const float* lnf_b  = (const float*)d_in[17];
    const float* head_w = (const float*)d_in[18];
    const float* head_b = (const float*)d_in[19];
    float* out = (float*)d_out;

    // workspace carve (~74.8 MB; round-2 proved >= 83.9 MB available)
    char* w = (char*)d_ws;
    float* X    = (float*)w;  w += (size_t)ROWS * DIMC * 4;       // 16.8 MB
    bf16*  XNh  = (bf16*)w;   w += (size_t)ROWS * DIMC * 2;       //  8.4 MB
    bf16*  QKVh = (bf16*)w;   w += (size_t)ROWS * 1536 * 2;       // 25.2 MB
    bf16*  Obh  = (bf16*)w;   w += (size_t)ROWS * DIMC * 2;       //  8.4 MB
    bf16*  xbf  = (bf16*)w;   w += (size_t)BATCH * SEQ * DIN * 2; // 12.6 MB
    bf16*  fc_wt  = (bf16*)w;
    bf16*  qkv_wt = fc_wt  + (size_t)DIN * DIMC;
    bf16*  out_wt = qkv_wt + (size_t)2 * DIMC * 1536;
    bf16*  ff1_wt = out_wt + (size_t)2 * DIMC * DIMC;
    bf16*  ff2_wt = ff1_wt + (size_t)2 * DIMC * DIMC;
    bf16*  Hbh  = Obh;   // alias: Ob dead after proj gemm

    dim3 blk(256);
    dim3 tb(32, 8);

    // x -> bf16
    cast_kernel<<<dim3((BATCH * SEQ * DIN / 4 + 255) / 256), blk, 0, stream>>>(
        x, xbf, BATCH * SEQ * DIN / 4);

    // weight transposes (+cast): W[K,N] fp32 -> Wt[N,K] bf16
    transpose_kernel<<<dim3(16, 24, 1), tb, 0, stream>>>(fc_w,  fc_wt,  DIN,  DIMC, (long)DIN * DIMC);
    transpose_kernel<<<dim3(48, 16, 2), tb, 0, stream>>>(qkv_w, qkv_wt, DIMC, 1536, (long)DIMC * 1536);
    transpose_kernel<<<dim3(16, 16, 2), tb, 0, stream>>>(out_w, out_wt, DIMC, DIMC, (long)DIMC * DIMC);
    transpose_kernel<<<dim3(16, 16, 2), tb, 0, stream>>>(ff1_w, ff1_wt, DIMC, DIMC, (long)DIMC * DIMC);
    transpose_kernel<<<dim3(16, 16, 2), tb, 0, stream>>>(ff2_w, ff2_wt, DIMC, DIMC, (long)DIMC * DIMC);

    // stem: fc + gelu -> X fp32 (remapped rows), cls fill
    gemm_bt<true, false, true, false><<<dim3(4, 64), blk, 0, stream>>>(
        xbf, fc_wt, fc_b, nullptr, X, nullptr, BATCH * SEQ, DIMC, DIN);
    cls_fill_kernel<<<dim3(BATCH), blk, 0, stream>>>(cls, X);

    for (int l = 0; l < DEPTH; ++l) {
        ln_kernel<<<dim3(ROWS), blk, 0, stream>>>(X, XNh, ln1_g + l * DIMC, ln1_b + l * DIMC);
        gemm_bt<false, false, false, true><<<dim3(12, 65), blk, 0, stream>>>(
            XNh, qkv_wt + (size_t)l * DIMC * 1536, nullptr, nullptr, nullptr, QKVh, ROWS, 1536, DIMC);
        attn2_kernel<<<dim3(SEQ1, NHEAD, BATCH), blk, 0, stream>>>(QKVh, lens, Obh);
        gemm_bt<false, true, false, false><<<dim3(4, 65), blk, 0, stream>>>(
            Obh, out_wt + (size_t)l * DIMC * DIMC, out_b + l * DIMC, X, X, nullptr, ROWS, DIMC, DIMC);
        ln_kernel<<<dim3(ROWS), blk, 0, stream>>>(X, XNh, ln2_g + l * DIMC, ln2_b + l * DIMC);
        gemm_bt<true, false, false, true><<<dim3(4, 65), blk, 0, stream>>>(
            XNh, ff1_wt + (size_t)l * DIMC * DIMC, ff1_b + l * DIMC, nullptr, nullptr, Hbh, ROWS, DIMC, DIMC);
        gemm_bt<false, true, false, false><<<dim3(4, 65), blk, 0, stream>>>(
            Hbh, ff2_wt + (size_t)l * DIMC * DIMC, ff2_b + l * DIMC, X, X, nullptr, ROWS, DIMC, DIMC);
    }
    head_kernel<<<dim3(BATCH), blk, 0, stream>>>(X, lnf_g, lnf_b, head_w, head_b, out);
}

// Round 7
// 911.915 us; speedup vs baseline: 16.8508x; 9.4787x over previous
//
#include <hip/hip_runtime.h>
#include <hip/hip_bf16.h>
#include <math.h>
#include <float.h>

typedef __hip_bfloat16 bf16;
using bf16x8 = __attribute__((ext_vector_type(8))) __bf16;
using f32x4  = __attribute__((ext_vector_type(4))) float;

constexpr int BATCH = 4;
constexpr int SEQ   = 2048;
constexpr int SEQ1  = 2049;
constexpr int DIN   = 768;
constexpr int DIMC  = 512;
constexpr int DEPTH = 2;
constexpr int NHEAD = 8;
constexpr int DHEAD = 64;
constexpr int ROWS  = BATCH * SEQ1;   // 8196
constexpr int VKP   = 2112;           // padded key stride for VT (33 tiles * 64)
constexpr float ATT_SCALE = 0.125f;
constexpr float NEGBIG = -1e30f;

__device__ __forceinline__ bf16x8 ld_frag(const bf16* p) { return *(const bf16x8*)p; }

// ---------------- cast fp32 -> bf16 (x stem input) ----------------
__global__ __launch_bounds__(256) void cast_kernel(const float* __restrict__ src,
                                                   bf16* __restrict__ dst, int n4) {
    int i = blockIdx.x * 256 + threadIdx.x;
    if (i < n4) {
        float4 v = ((const float4*)src)[i];
        dst[i * 4 + 0] = __float2bfloat16(v.x);
        dst[i * 4 + 1] = __float2bfloat16(v.y);
        dst[i * 4 + 2] = __float2bfloat16(v.z);
        dst[i * 4 + 3] = __float2bfloat16(v.w);
    }
}

// ---------------- weight transpose + cast: src[R][C] fp32 -> dst[C][R] bf16, z batches ----------------
__global__ __launch_bounds__(256) void wt_transpose_kernel(
    const float* __restrict__ src, bf16* __restrict__ dst,
    int R, int C, long zstride) {
    __shared__ bf16 tile[32][33];
    int z = blockIdx.z;
    const float* s = src + (size_t)z * zstride;
    bf16* d = dst + (size_t)z * zstride;
    int tx = threadIdx.x, ty = threadIdx.y;
    int c0 = blockIdx.x * 32, r0 = blockIdx.y * 32;
    int c = c0 + tx;
#pragma unroll
    for (int rr = ty; rr < 32; rr += 8) {
        int r = r0 + rr;
        tile[rr][tx] = (r < R && c < C) ? __float2bfloat16(s[(size_t)r * C + c])
                                        : __float2bfloat16(0.f);
    }
    __syncthreads();
    int rc = r0 + tx;
#pragma unroll
    for (int cc = ty; cc < 32; cc += 8) {
        int oc = c0 + cc;
        if (rc < R && oc < C) d[(size_t)oc * R + rc] = tile[tx][cc];
    }
}

// ---------------- V transpose: QKV V-part [SEQ1][64] per (b,h) -> VT[b*8+h][64][VKP], zero-padded keys ----------------
__global__ __launch_bounds__(256) void vt_transpose_kernel(
    const bf16* __restrict__ QKV, bf16* __restrict__ VT) {
    __shared__ bf16 tile[32][33];
    int z = blockIdx.z;                       // b*8+h
    int bb = z >> 3, hh = z & 7;
    const bf16* s = QKV + (size_t)bb * SEQ1 * 1536 + 1024 + hh * 64;
    bf16* d = VT + (size_t)z * 64 * VKP;
    int tx = threadIdx.x, ty = threadIdx.y;
    int c0 = blockIdx.x * 32, r0 = blockIdx.y * 32;   // c: dim, r: key
    int c = c0 + tx;
#pragma unroll
    for (int rr = ty; rr < 32; rr += 8) {
        int r = r0 + rr;
        tile[rr][tx] = (r < SEQ1) ? s[(size_t)r * 1536 + c] : __float2bfloat16(0.f);
    }
    __syncthreads();
    int rc = r0 + tx;                          // key index in output row
#pragma unroll
    for (int cc = ty; cc < 32; cc += 8) {
        int oc = c0 + cc;                      // dim
        if (rc < VKP) d[(size_t)oc * VKP + rc] = tile[tx][cc];
    }
}

// ---------------- cls fill (fp32) ----------------
__global__ void cls_fill_kernel(const float* __restrict__ cls, float* __restrict__ X) {
    int b = blockIdx.x;
    for (int d = threadIdx.x; d < DIMC; d += blockDim.x)
        X[(size_t)b * SEQ1 * DIMC + d] = cls[d];
}

// ---------------- MFMA GEMM: C[M,N] = A[M,K](bf16) @ Bt[N,K]^T (+bias fp32)(gelu)(+resid fp32) ----------------
template<bool GELU_, bool RESID, bool REMAP, bool OBF>
__global__ __launch_bounds__(256) void gemm_bt(
    const bf16* __restrict__ A, const bf16* __restrict__ Bt,
    const float* __restrict__ bias, const float* __restrict__ resid,
    float* __restrict__ Cf, bf16* __restrict__ Ch, int M, int N, int K) {
    __shared__ __align__(16) bf16 As[4096];
    __shared__ __align__(16) bf16 Bs[4096];
    int tid = threadIdx.x;
    int ln = tid & 63, wv = tid >> 6;
    int wr = wv >> 1, wc = wv & 1;
    int l15 = ln & 15, l4 = ln >> 4;
    int m0 = blockIdx.y * 128, n0 = blockIdx.x * 128;

    f32x4 acc[4][4];
#pragma unroll
    for (int i = 0; i < 4; ++i)
#pragma unroll
        for (int j = 0; j < 4; ++j) acc[i][j] = {0.f, 0.f, 0.f, 0.f};

    int aslot[4], bslot[4];
#pragma unroll
    for (int i = 0; i < 4; ++i) {
        int m = wr * 64 + i * 16 + l15;
        aslot[i] = m * 4 + (l4 ^ ((m >> 1) & 3));
        int n = wc * 64 + i * 16 + l15;
        bslot[i] = n * 4 + (l4 ^ ((n >> 1) & 3));
    }

    for (int k0 = 0; k0 < K; k0 += 32) {
#pragma unroll
        for (int r = 0; r < 2; ++r) {
            int s = r * 256 + tid;
            int m = s >> 2, c = s & 3;
            int kb = c ^ ((m >> 1) & 3);
            int gm = m0 + m; if (gm > M - 1) gm = M - 1;
            uint4 v = *(const uint4*)(A + (size_t)gm * K + k0 + kb * 8);
            *(uint4*)&As[s * 8] = v;
        }
#pragma unroll
        for (int r = 0; r < 2; ++r) {
            int s = r * 256 + tid;
            int n = s >> 2, c = s & 3;
            int kb = c ^ ((n >> 1) & 3);
            uint4 v = *(const uint4*)(Bt + (size_t)(n0 + n) * K + k0 + kb * 8);
            *(uint4*)&Bs[s * 8] = v;
        }
        __syncthreads();
        bf16x8 af[4], bfr[4];
#pragma unroll
        for (int i = 0; i < 4; ++i) af[i] = ld_frag(&As[aslot[i] * 8]);
#pragma unroll
        for (int j = 0; j < 4; ++j) bfr[j] = ld_frag(&Bs[bslot[j] * 8]);
#pragma unroll
        for (int i = 0; i < 4; ++i)
#pragma unroll
            for (int j = 0; j < 4; ++j)
                acc[i][j] = __builtin_amdgcn_mfma_f32_16x16x32_bf16(af[i], bfr[j], acc[i][j], 0, 0, 0);
        __syncthreads();
    }

#pragma unroll
    for (int i = 0; i < 4; ++i) {
#pragma unroll
        for (int j = 0; j < 4; ++j) {
            int gn = n0 + wc * 64 + j * 16 + l15;
            float bb = bias ? bias[gn] : 0.f;
#pragma unroll
            for (int r = 0; r < 4; ++r) {
                int gm = m0 + wr * 64 + i * 16 + l4 * 4 + r;
                if (gm >= M) continue;
                float v = acc[i][j][r] + bb;
                if (GELU_) v = 0.5f * v * (1.f + erff(v * 0.70710678118654752f));
                size_t orow = gm;
                if (REMAP) { int b_ = gm >> 11; orow = (size_t)b_ * SEQ1 + (gm & 2047) + 1; }
                size_t oi = orow * (size_t)N + gn;
                if (RESID) v += resid[oi];
                if (OBF) Ch[oi] = __float2bfloat16(v); else Cf[oi] = v;
            }
        }
    }
}

// ---------------- LayerNorm: X fp32 -> XN bf16 (g,b fp32) ----------------
__global__ __launch_bounds__(256) void ln_kernel(const float* __restrict__ Xin, bf16* __restrict__ Xout,
                          const float* __restrict__ g, const float* __restrict__ bb) {
    int row = blockIdx.x;
    int t = threadIdx.x;
    const float* xr = Xin + (size_t)row * DIMC;
    float v0 = xr[t], v1 = xr[t + 256];
    __shared__ float red[256];
    red[t] = v0 + v1;
    __syncthreads();
    for (int w = 128; w > 0; w >>= 1) { if (t < w) red[t] += red[t + w]; __syncthreads(); }
    float mean = red[0] * (1.f / 512.f);
    __syncthreads();
    float d0 = v0 - mean, d1 = v1 - mean;
    red[t] = d0 * d0 + d1 * d1;
    __syncthreads();
    for (int w = 128; w > 0; w >>= 1) { if (t < w) red[t] += red[t + w]; __syncthreads(); }
    float rinv = rsqrtf(red[0] * (1.f / 512.f) + 1e-5f);
    bf16* orow = Xout + (size_t)row * DIMC;
    orow[t]       = __float2bfloat16(d0 * rinv * g[t]       + bb[t]);
    orow[t + 256] = __float2bfloat16(d1 * rinv * g[t + 256] + bb[t + 256]);
}

// ---------------- MFMA flash attention: block = (64 queries, head, batch), 4 waves ----------------
__global__ __launch_bounds__(256) void attn_kernel(
    const bf16* __restrict__ QKV, const bf16* __restrict__ VT,
    const int* __restrict__ lens, bf16* __restrict__ O) {
    constexpr int KS = 72;   // LDS row stride (bf16)
    __shared__ __align__(16) bf16 Ks[64 * KS];
    __shared__ __align__(16) bf16 Vs[64 * KS];       // V^T tile: [dim][key]
    __shared__ __align__(16) bf16 Pw[4 * 16 * KS];
    int tid = threadIdx.x, ln = tid & 63, wv = tid >> 6;
    int l15 = ln & 15, l4 = ln >> 4;
    int q0 = blockIdx.x * 64, h = blockIdx.y, b = blockIdx.z;
    int len1 = lens[b] + 1;
    const bf16* qkv_b = QKV + (size_t)b * SEQ1 * 1536;

    uint4 z4 = make_uint4(0u, 0u, 0u, 0u);
    uint4 q0v = z4, q1v = z4;
    int qrow = q0 + wv * 16 + l15;
    if (qrow < SEQ1) {
        const bf16* qp = qkv_b + (size_t)qrow * 1536 + h * 64 + l4 * 8;
        q0v = *(const uint4*)qp;
        q1v = *(const uint4*)(qp + 32);
    }
    bf16x8 aq0 = __builtin_bit_cast(bf16x8, q0v);
    bf16x8 aq1 = __builtin_bit_cast(bf16x8, q1v);

    float mrun[4], lrun[4];
    f32x4 oacc[4];
    bool qpad[4];
#pragma unroll
    for (int r = 0; r < 4; ++r) {
        mrun[r] = NEGBIG; lrun[r] = 0.f;
        oacc[r] = {0.f, 0.f, 0.f, 0.f};
        qpad[r] = (q0 + wv * 16 + l4 * 4 + r) >= len1;
    }

    for (int kt = 0; kt < 33; ++kt) {
        int k0 = kt * 64;
#pragma unroll
        for (int rr = 0; rr < 2; ++rr) {
            int idx = rr * 256 + tid;
            int row = idx >> 3, seg = idx & 7;
            uint4 kv = z4;
            if (k0 + row < SEQ1)
                kv = *(const uint4*)(qkv_b + (size_t)(k0 + row) * 1536 + 512 + h * 64 + seg * 8);
            *(uint4*)&Ks[row * KS + seg * 8] = kv;
            uint4 vv = *(const uint4*)(VT + ((size_t)(b * 8 + h) * 64 + row) * VKP + k0 + seg * 8);
            *(uint4*)&Vs[row * KS + seg * 8] = vv;
        }
        __syncthreads();

        // S = Q K^T
        f32x4 sacc[4];
#pragma unroll
        for (int jt = 0; jt < 4; ++jt) {
            sacc[jt] = {0.f, 0.f, 0.f, 0.f};
            bf16x8 bk0 = ld_frag(&Ks[(jt * 16 + l15) * KS + l4 * 8]);
            bf16x8 bk1 = ld_frag(&Ks[(jt * 16 + l15) * KS + 32 + l4 * 8]);
            sacc[jt] = __builtin_amdgcn_mfma_f32_16x16x32_bf16(aq0, bk0, sacc[jt], 0, 0, 0);
            sacc[jt] = __builtin_amdgcn_mfma_f32_16x16x32_bf16(aq1, bk1, sacc[jt], 0, 0, 0);
        }

        // online softmax per register row r (row = l4*4+r, cols = k0 + jt*16 + l15)
#pragma unroll
        for (int r = 0; r < 4; ++r) {
            float sj[4];
#pragma unroll
            for (int jt = 0; jt < 4; ++jt) {
                int j = k0 + jt * 16 + l15;
                float sv = sacc[jt][r] * ATT_SCALE;
                if (j >= SEQ1 || (qpad[r] && j >= len1)) sv = NEGBIG;
                sj[jt] = sv;
            }
            float mx = fmaxf(fmaxf(sj[0], sj[1]), fmaxf(sj[2], sj[3]));
#pragma unroll
            for (int off = 1; off < 16; off <<= 1) mx = fmaxf(mx, __shfl_xor(mx, off, 16));
            float mnew = fmaxf(mrun[r], mx);
            float alpha = __expf(mrun[r] - mnew);
            float rs = 0.f;
#pragma unroll
            for (int jt = 0; jt < 4; ++jt) {
                float ex = sj[jt] - mnew;
                float p = (ex < -80.f) ? 0.f : __expf(ex);
                rs += p;
                Pw[wv * 16 * KS + (l4 * 4 + r) * KS + jt * 16 + l15] = __float2bfloat16(p);
            }
#pragma unroll
            for (int off = 1; off < 16; off <<= 1) rs += __shfl_xor(rs, off, 16);
            lrun[r] = lrun[r] * alpha + rs;
            mrun[r] = mnew;
#pragma unroll
            for (int t = 0; t < 4; ++t) oacc[t][r] *= alpha;
        }
        __syncthreads();

        // O += P V
        bf16x8 ap0 = ld_frag(&Pw[wv * 16 * KS + l15 * KS + l4 * 8]);
        bf16x8 ap1 = ld_frag(&Pw[wv * 16 * KS + l15 * KS + 32 + l4 * 8]);
#pragma unroll
        for (int t = 0; t < 4; ++t) {
            bf16x8 bv0 = ld_frag(&Vs[(t * 16 + l15) * KS + l4 * 8]);
            bf16x8 bv1 = ld_frag(&Vs[(t * 16 + l15) * KS + 32 + l4 * 8]);
            oacc[t] = __builtin_amdgcn_mfma_f32_16x16x32_bf16(ap0, bv0, oacc[t], 0, 0, 0);
            oacc[t] = __builtin_amdgcn_mfma_f32_16x16x32_bf16(ap1, bv1, oacc[t], 0, 0, 0);
        }
        __syncthreads();
    }

#pragma unroll
    for (int r = 0; r < 4; ++r) {
        int q = q0 + wv * 16 + l4 * 4 + r;
        if (q >= SEQ1) continue;
        float rl = (lrun[r] > 0.f) ? 1.f / lrun[r] : 0.f;
#pragma unroll
        for (int t = 0; t < 4; ++t)
            O[((size_t)b * SEQ1 + q) * DIMC + h * 64 + t * 16 + l15] =
                __float2bfloat16(oacc[t][r] * rl);
    }
}

// ---------------- fused final LN + head (cls row only), fp32 ----------------
__global__ __launch_bounds__(256) void head_kernel(const float* __restrict__ X,
                            const float* __restrict__ g, const float* __restrict__ bb,
                            const float* __restrict__ hw, const float* __restrict__ hb,
                            float* __restrict__ out) {
    int b = blockIdx.x, t = threadIdx.x;
    const float* xr = X + (size_t)b * SEQ1 * DIMC;
    float v0 = xr[t], v1 = xr[t + 256];
    __shared__ float red[256];
    red[t] = v0 + v1;
    __syncthreads();
    for (int w = 128; w > 0; w >>= 1) { if (t < w) red[t] += red[t + w]; __syncthreads(); }
    float mean = red[0] * (1.f / 512.f);
    __syncthreads();
    float d0 = v0 - mean, d1 = v1 - mean;
    red[t] = d0 * d0 + d1 * d1;
    __syncthreads();
    for (int w = 128; w > 0; w >>= 1) { if (t < w) red[t] += red[t + w]; __syncthreads(); }
    float rinv = rsqrtf(red[0] * (1.f / 512.f) + 1e-5f);
    __syncthreads();
    float xn0 = d0 * rinv * g[t] + bb[t];
    float xn1 = d1 * rinv * g[t + 256] + bb[t + 256];
    float p0 = xn0 * hw[t * 2]     + xn1 * hw[(t + 256) * 2];
    float p1 = xn0 * hw[t * 2 + 1] + xn1 * hw[(t + 256) * 2 + 1];
    __shared__ float r0[256], r1[256];
    r0[t] = p0; r1[t] = p1;
    __syncthreads();
    for (int w = 128; w > 0; w >>= 1) { if (t < w) { r0[t] += r0[t + w]; r1[t] += r1[t + w]; } __syncthreads(); }
    if (t == 0) {
        out[b * 2 + 0] = r0[0] + hb[0];
        out[b * 2 + 1] = r1[0] + hb[1];
    }
}

extern "C" void kernel_launch(void* const* d_in, const int* in_sizes, int n_in,
                              void* d_out, int out_size, void* d_ws, size_t ws_size,
                              hipStream_t stream) {
    const float* x      = (const float*)d_in[0];
    const int*   lens   = (const int*)d_in[1];
    const float* cls    = (const float*)d_in[2];
    const float* fc_w   = (const float*)d_in[3];
    const float* fc_b   = (const float*)d_in[4];
    const float* ln1_g  = (const float*)d_in[5];
    const float* ln1_b  = (const float*)d_in[6];
    const float* qkv_w  = (const float*)d_in[7];
    const float* out_w  = (const float*)d_in[8];
    const float* out_b  = (const float*)d_in[9];
    const float* ln2_g  = (const float*)d_in[10];
    const float* ln2_b  = (const float*)d_in[11];
    const float* ff1_w  = (const float*)d_in[12];
    const float* ff1_b  = (const float*)d_in[13];
    const float* ff2_w  = (const float*)d_in[14];
    const float* ff2_b  = (const float*)d_in[15];
    const float* lnf_g  = (const float*)d_in[16];
    const float* lnf_b  = (const float*)d_in[17];
    const float* head_w = (const float*)d_in[18];
    const float* head_b = (const float*)d_in[19];
    float* out = (float*)d_out;

    // workspace carve (~78.4 MB; 83.9 MB proven available in R2)
    char* w = (char*)d_ws;
    float* X    = (float*)w;  w += (size_t)ROWS * DIMC * 4;       // 16.8 MB
    bf16*  XNh  = (bf16*)w;   w += (size_t)ROWS * DIMC * 2;       //  8.4 MB
    bf16*  QKVh = (bf16*)w;   w += (size_t)ROWS * 1536 * 2;       // 25.2 MB
    bf16*  Obh  = (bf16*)w;   w += (size_t)ROWS * DIMC * 2;       //  8.4 MB
    bf16*  xbf  = (bf16*)w;   w += (size_t)BATCH * SEQ * DIN * 2; // 12.6 MB
    bf16*  VT   = xbf;        // alias: xbf dead after stem gemm; VT needs 8.65 MB <= 12.6 MB
    bf16*  fc_wt  = (bf16*)w;
    bf16*  qkv_wt = fc_wt  + (size_t)DIN * DIMC;
    bf16*  out_wt = qkv_wt + (size_t)2 * DIMC * 1536;
    bf16*  ff1_wt = out_wt + (size_t)2 * DIMC * DIMC;
    bf16*  ff2_wt = ff1_wt + (size_t)2 * DIMC * DIMC;
    bf16*  Hbh  = Obh;        // alias: Ob dead after proj gemm

    dim3 blk(256);
    dim3 tb(32, 8);

    cast_kernel<<<dim3((BATCH * SEQ * DIN / 4 + 255) / 256), blk, 0, stream>>>(
        x, xbf, BATCH * SEQ * DIN / 4);

    wt_transpose_kernel<<<dim3(16, 24, 1), tb, 0, stream>>>(fc_w,  fc_wt,  DIN,  DIMC, (long)DIN * DIMC);
    wt_transpose_kernel<<<dim3(48, 16, 2), tb, 0, stream>>>(qkv_w, qkv_wt, DIMC, 1536, (long)DIMC * 1536);
    wt_transpose_kernel<<<dim3(16, 16, 2), tb, 0, stream>>>(out_w, out_wt, DIMC, DIMC, (long)DIMC * DIMC);
    wt_transpose_kernel<<<dim3(16, 16, 2), tb, 0, stream>>>(ff1_w, ff1_wt, DIMC, DIMC, (long)DIMC * DIMC);
    wt_transpose_kernel<<<dim3(16, 16, 2), tb, 0, stream>>>(ff2_w, ff2_wt, DIMC, DIMC, (long)DIMC * DIMC);

    // stem: fc + gelu -> X fp32 (remapped rows), then cls fill
    gemm_bt<true, false, true, false><<<dim3(4, 64), blk, 0, stream>>>(
        xbf, fc_wt, fc_b, nullptr, X, nullptr, BATCH * SEQ, DIMC, DIN);
    cls_fill_kernel<<<dim3(BATCH), blk, 0, stream>>>(cls, X);

    for (int l = 0; l < DEPTH; ++l) {
        ln_kernel<<<dim3(ROWS), blk, 0, stream>>>(X, XNh, ln1_g + l * DIMC, ln1_b + l * DIMC);
        gemm_bt<false, false, false, true><<<dim3(12, 65), blk, 0, stream>>>(
            XNh, qkv_wt + (size_t)l * DIMC * 1536, nullptr, nullptr, nullptr, QKVh, ROWS, 1536, DIMC);
        vt_transpose_kernel<<<dim3(2, 66, 32), tb, 0, stream>>>(QKVh, VT);
        attn_kernel<<<dim3(33, NHEAD, BATCH), blk, 0, stream>>>(QKVh, VT, lens, Obh);
        gemm_bt<false, true, false, false><<<dim3(4, 65), blk, 0, stream>>>(
            Obh, out_wt + (size_t)l * DIMC * DIMC, out_b + l * DIMC, X, X, nullptr, ROWS, DIMC, DIMC);
        ln_kernel<<<dim3(ROWS), blk, 0, stream>>>(X, XNh, ln2_g + l * DIMC, ln2_b + l * DIMC);
        gemm_bt<true, false, false, true><<<dim3(4, 65), blk, 0, stream>>>(
            XNh, ff1_wt + (size_t)l * DIMC * DIMC, ff1_b + l * DIMC, nullptr, nullptr, Hbh, ROWS, DIMC, DIMC);
        gemm_bt<false, true, false, false><<<dim3(4, 65), blk, 0, stream>>>(
            Hbh, ff2_wt + (size_t)l * DIMC * DIMC, ff2_b + l * DIMC, X, X, nullptr, ROWS, DIMC, DIMC);
    }
    head_kernel<<<dim3(BATCH), blk, 0, stream>>>(X, lnf_g, lnf_b, head_w, head_b, out);
}

// Round 8
// 765.926 us; speedup vs baseline: 20.0627x; 1.1906x over previous
//
#include <hip/hip_runtime.h>
#include <hip/hip_bf16.h>
#include <math.h>
#include <float.h>

typedef __hip_bfloat16 bf16;
using bf16x8 = __attribute__((ext_vector_type(8))) __bf16;
using f32x4  = __attribute__((ext_vector_type(4))) float;

constexpr int BATCH = 4;
constexpr int SEQ   = 2048;
constexpr int SEQ1  = 2049;
constexpr int DIN   = 768;
constexpr int DIMC  = 512;
constexpr int DEPTH = 2;
constexpr int NHEAD = 8;
constexpr int DHEAD = 64;
constexpr int ROWS  = BATCH * SEQ1;   // 8196
constexpr int VKP   = 2112;           // padded key stride for VT (33 tiles * 64)
constexpr float ATT_SCALE = 0.125f;
constexpr float NEGBIG = -1e30f;

__device__ __forceinline__ bf16x8 ld_frag(const bf16* p) { return *(const bf16x8*)p; }

// ---------------- cast fp32 -> bf16 (x stem input) ----------------
__global__ __launch_bounds__(256) void cast_kernel(const float* __restrict__ src,
                                                   bf16* __restrict__ dst, int n4) {
    int i = blockIdx.x * 256 + threadIdx.x;
    if (i < n4) {
        float4 v = ((const float4*)src)[i];
        dst[i * 4 + 0] = __float2bfloat16(v.x);
        dst[i * 4 + 1] = __float2bfloat16(v.y);
        dst[i * 4 + 2] = __float2bfloat16(v.z);
        dst[i * 4 + 3] = __float2bfloat16(v.w);
    }
}

// ---------------- weight transpose + cast: src[R][C] fp32 -> dst[C][R] bf16, z batches ----------------
__global__ __launch_bounds__(256) void wt_transpose_kernel(
    const float* __restrict__ src, bf16* __restrict__ dst,
    int R, int C, long zstride) {
    __shared__ bf16 tile[32][33];
    int z = blockIdx.z;
    const float* s = src + (size_t)z * zstride;
    bf16* d = dst + (size_t)z * zstride;
    int tx = threadIdx.x, ty = threadIdx.y;
    int c0 = blockIdx.x * 32, r0 = blockIdx.y * 32;
    int c = c0 + tx;
#pragma unroll
    for (int rr = ty; rr < 32; rr += 8) {
        int r = r0 + rr;
        tile[rr][tx] = (r < R && c < C) ? __float2bfloat16(s[(size_t)r * C + c])
                                        : __float2bfloat16(0.f);
    }
    __syncthreads();
    int rc = r0 + tx;
#pragma unroll
    for (int cc = ty; cc < 32; cc += 8) {
        int oc = c0 + cc;
        if (rc < R && oc < C) d[(size_t)oc * R + rc] = tile[tx][cc];
    }
}

// ---------------- V transpose: QKV V-part [SEQ1][64] per (b,h) -> VT[b*8+h][64][VKP], zero-padded keys ----------------
__global__ __launch_bounds__(256) void vt_transpose_kernel(
    const bf16* __restrict__ QKV, bf16* __restrict__ VT) {
    __shared__ bf16 tile[32][33];
    int z = blockIdx.z;                       // b*8+h
    int bb = z >> 3, hh = z & 7;
    const bf16* s = QKV + (size_t)bb * SEQ1 * 1536 + 1024 + hh * 64;
    bf16* d = VT + (size_t)z * 64 * VKP;
    int tx = threadIdx.x, ty = threadIdx.y;
    int c0 = blockIdx.x * 32, r0 = blockIdx.y * 32;   // c: dim, r: key
    int c = c0 + tx;
#pragma unroll
    for (int rr = ty; rr < 32; rr += 8) {
        int r = r0 + rr;
        tile[rr][tx] = (r < SEQ1) ? s[(size_t)r * 1536 + c] : __float2bfloat16(0.f);
    }
    __syncthreads();
    int rc = r0 + tx;                          // key index in output row
#pragma unroll
    for (int cc = ty; cc < 32; cc += 8) {
        int oc = c0 + cc;                      // dim
        if (rc < VKP) d[(size_t)oc * VKP + rc] = tile[tx][cc];
    }
}

// ---------------- cls fill (fp32) ----------------
__global__ void cls_fill_kernel(const float* __restrict__ cls, float* __restrict__ X) {
    int b = blockIdx.x;
    for (int d = threadIdx.x; d < DIMC; d += blockDim.x)
        X[(size_t)b * SEQ1 * DIMC + d] = cls[d];
}

// ---------------- MFMA GEMM: C[M,N] = A[M,K](bf16) @ Bt[N,K]^T (+bias fp32)(gelu)(+resid fp32) ----------------
template<bool GELU_, bool RESID, bool REMAP, bool OBF>
__global__ __launch_bounds__(256) void gemm_bt(
    const bf16* __restrict__ A, const bf16* __restrict__ Bt,
    const float* __restrict__ bias, const float* __restrict__ resid,
    float* __restrict__ Cf, bf16* __restrict__ Ch, int M, int N, int K) {
    __shared__ __align__(16) bf16 As[4096];
    __shared__ __align__(16) bf16 Bs[4096];
    int tid = threadIdx.x;
    int ln = tid & 63, wv = tid >> 6;
    int wr = wv >> 1, wc = wv & 1;
    int l15 = ln & 15, l4 = ln >> 4;
    int m0 = blockIdx.y * 128, n0 = blockIdx.x * 128;

    f32x4 acc[4][4];
#pragma unroll
    for (int i = 0; i < 4; ++i)
#pragma unroll
        for (int j = 0; j < 4; ++j) acc[i][j] = {0.f, 0.f, 0.f, 0.f};

    int aslot[4], bslot[4];
#pragma unroll
    for (int i = 0; i < 4; ++i) {
        int m = wr * 64 + i * 16 + l15;
        aslot[i] = m * 4 + (l4 ^ ((m >> 1) & 3));
        int n = wc * 64 + i * 16 + l15;
        bslot[i] = n * 4 + (l4 ^ ((n >> 1) & 3));
    }

    for (int k0 = 0; k0 < K; k0 += 32) {
#pragma unroll
        for (int r = 0; r < 2; ++r) {
            int s = r * 256 + tid;
            int m = s >> 2, c = s & 3;
            int kb = c ^ ((m >> 1) & 3);
            int gm = m0 + m; if (gm > M - 1) gm = M - 1;
            uint4 v = *(const uint4*)(A + (size_t)gm * K + k0 + kb * 8);
            *(uint4*)&As[s * 8] = v;
        }
#pragma unroll
        for (int r = 0; r < 2; ++r) {
            int s = r * 256 + tid;
            int n = s >> 2, c = s & 3;
            int kb = c ^ ((n >> 1) & 3);
            uint4 v = *(const uint4*)(Bt + (size_t)(n0 + n) * K + k0 + kb * 8);
            *(uint4*)&Bs[s * 8] = v;
        }
        __syncthreads();
        bf16x8 af[4], bfr[4];
#pragma unroll
        for (int i = 0; i < 4; ++i) af[i] = ld_frag(&As[aslot[i] * 8]);
#pragma unroll
        for (int j = 0; j < 4; ++j) bfr[j] = ld_frag(&Bs[bslot[j] * 8]);
#pragma unroll
        for (int i = 0; i < 4; ++i)
#pragma unroll
            for (int j = 0; j < 4; ++j)
                acc[i][j] = __builtin_amdgcn_mfma_f32_16x16x32_bf16(af[i], bfr[j], acc[i][j], 0, 0, 0);
        __syncthreads();
    }

#pragma unroll
    for (int i = 0; i < 4; ++i) {
#pragma unroll
        for (int j = 0; j < 4; ++j) {
            int gn = n0 + wc * 64 + j * 16 + l15;
            float bb = bias ? bias[gn] : 0.f;
#pragma unroll
            for (int r = 0; r < 4; ++r) {
                int gm = m0 + wr * 64 + i * 16 + l4 * 4 + r;
                if (gm >= M) continue;
                float v = acc[i][j][r] + bb;
                if (GELU_) v = 0.5f * v * (1.f + erff(v * 0.70710678118654752f));
                size_t orow = gm;
                if (REMAP) { int b_ = gm >> 11; orow = (size_t)b_ * SEQ1 + (gm & 2047) + 1; }
                size_t oi = orow * (size_t)N + gn;
                if (RESID) v += resid[oi];
                if (OBF) Ch[oi] = __float2bfloat16(v); else Cf[oi] = v;
            }
        }
    }
}

// ---------------- LayerNorm: X fp32 -> XN bf16 (g,b fp32) ----------------
__global__ __launch_bounds__(256) void ln_kernel(const float* __restrict__ Xin, bf16* __restrict__ Xout,
                          const float* __restrict__ g, const float* __restrict__ bb) {
    int row = blockIdx.x;
    int t = threadIdx.x;
    const float* xr = Xin + (size_t)row * DIMC;
    float v0 = xr[t], v1 = xr[t + 256];
    __shared__ float red[256];
    red[t] = v0 + v1;
    __syncthreads();
    for (int w = 128; w > 0; w >>= 1) { if (t < w) red[t] += red[t + w]; __syncthreads(); }
    float mean = red[0] * (1.f / 512.f);
    __syncthreads();
    float d0 = v0 - mean, d1 = v1 - mean;
    red[t] = d0 * d0 + d1 * d1;
    __syncthreads();
    for (int w = 128; w > 0; w >>= 1) { if (t < w) red[t] += red[t + w]; __syncthreads(); }
    float rinv = rsqrtf(red[0] * (1.f / 512.f) + 1e-5f);
    bf16* orow = Xout + (size_t)row * DIMC;
    orow[t]       = __float2bfloat16(d0 * rinv * g[t]       + bb[t]);
    orow[t + 256] = __float2bfloat16(d1 * rinv * g[t + 256] + bb[t + 256]);
}

// ---------------- MFMA flash attention v2: S^T trick, register PV, 1 barrier/tile ----------------
__global__ __launch_bounds__(256, 4) void attn_kernel(
    const bf16* __restrict__ QKV, const bf16* __restrict__ VT,
    const int* __restrict__ lens, bf16* __restrict__ O) {
    constexpr int KS = 72;
    __shared__ __align__(16) bf16 Ks[2][64 * KS];
    __shared__ __align__(16) bf16 Vs[2][64 * KS];   // V^T tile: [dim][key]
    int tid = threadIdx.x, ln = tid & 63, wv = tid >> 6;
    int l15 = ln & 15, l4 = ln >> 4;
    int q0 = blockIdx.x * 64, h = blockIdx.y, b = blockIdx.z;
    int len1 = lens[b] + 1;
    const bf16* qkv_b = QKV + (size_t)b * SEQ1 * 1536;
    const bf16* vt_b  = VT + (size_t)(b * 8 + h) * 64 * VKP;

    uint4 z4 = make_uint4(0u, 0u, 0u, 0u);
    uint4 q0v = z4, q1v = z4;
    int qrow = q0 + wv * 16 + l15;
    if (qrow < SEQ1) {
        const bf16* qp = qkv_b + (size_t)qrow * 1536 + h * 64 + l4 * 8;
        q0v = *(const uint4*)qp;
        q1v = *(const uint4*)(qp + 32);
    }
    bf16x8 bq0 = __builtin_bit_cast(bf16x8, q0v);
    bf16x8 bq1 = __builtin_bit_cast(bf16x8, q1v);
    bool qpad = (qrow >= len1);

    float mrun = NEGBIG, lrun = 0.f;
    f32x4 oaccT[4];
#pragma unroll
    for (int t = 0; t < 4; ++t) oaccT[t] = {0.f, 0.f, 0.f, 0.f};

    uint4 kr[2], vr[2];
    int srow[2], sseg[2], krow[2];
#pragma unroll
    for (int rr = 0; rr < 2; ++rr) {
        int idx = rr * 256 + tid;
        int row = idx >> 3, seg = idx & 7;
        srow[rr] = row; sseg[rr] = seg;
        int pb = row >> 5, w = row & 31;
        krow[rr] = pb * 32 + ((w >> 2) & 1) * 16 + (w >> 3) * 4 + (w & 3);  // permuted K row
    }

#pragma unroll
    for (int rr = 0; rr < 2; ++rr) {
        kr[rr] = (srow[rr] < SEQ1)
            ? *(const uint4*)(qkv_b + (size_t)srow[rr] * 1536 + 512 + h * 64 + sseg[rr] * 8) : z4;
        vr[rr] = *(const uint4*)(vt_b + (size_t)srow[rr] * VKP + sseg[rr] * 8);
    }
#pragma unroll
    for (int rr = 0; rr < 2; ++rr) {
        *(uint4*)&Ks[0][krow[rr] * KS + sseg[rr] * 8] = kr[rr];
        *(uint4*)&Vs[0][srow[rr] * KS + sseg[rr] * 8] = vr[rr];
    }
    __syncthreads();

    for (int kt = 0; kt < 33; ++kt) {
        int k0 = kt * 64;
        int buf = kt & 1;
        if (kt < 32) {
            int kn = k0 + 64;
#pragma unroll
            for (int rr = 0; rr < 2; ++rr) {
                kr[rr] = (kn + srow[rr] < SEQ1)
                    ? *(const uint4*)(qkv_b + (size_t)(kn + srow[rr]) * 1536 + 512 + h * 64 + sseg[rr] * 8) : z4;
                vr[rr] = *(const uint4*)(vt_b + (size_t)srow[rr] * VKP + kn + sseg[rr] * 8);
            }
        }

        // S^T = K Q^T : subtile (pb,s) holds keys k0 + pb*32 + l4*8 + s*4 + r at col q=l15
        f32x4 sacc[2][2];
#pragma unroll
        for (int pb = 0; pb < 2; ++pb)
#pragma unroll
            for (int s = 0; s < 2; ++s) {
                int R = pb * 32 + s * 16 + l15;
                f32x4 a = {0.f, 0.f, 0.f, 0.f};
                bf16x8 kf0 = ld_frag(&Ks[buf][R * KS + l4 * 8]);
                bf16x8 kf1 = ld_frag(&Ks[buf][R * KS + 32 + l4 * 8]);
                a = __builtin_amdgcn_mfma_f32_16x16x32_bf16(kf0, bq0, a, 0, 0, 0);
                a = __builtin_amdgcn_mfma_f32_16x16x32_bf16(kf1, bq1, a, 0, 0, 0);
                sacc[pb][s] = a;
            }

        // online softmax: one q per lane, 16 scores; cross-quad reduce = 2 shuffles
        float sv[2][2][4];
        float mx = NEGBIG;
#pragma unroll
        for (int pb = 0; pb < 2; ++pb)
#pragma unroll
            for (int s = 0; s < 2; ++s)
#pragma unroll
                for (int r = 0; r < 4; ++r) {
                    int j = k0 + pb * 32 + l4 * 8 + s * 4 + r;
                    float v = sacc[pb][s][r] * ATT_SCALE;
                    if (j >= SEQ1 || (qpad && j >= len1)) v = NEGBIG;
                    sv[pb][s][r] = v;
                    mx = fmaxf(mx, v);
                }
        mx = fmaxf(mx, __shfl_xor(mx, 16, 64));
        mx = fmaxf(mx, __shfl_xor(mx, 32, 64));
        float mnew = fmaxf(mrun, mx);
        float alpha = __expf(mrun - mnew);
        float rs = 0.f;
        unsigned short pk[2][8];
#pragma unroll
        for (int pb = 0; pb < 2; ++pb)
#pragma unroll
            for (int s = 0; s < 2; ++s)
#pragma unroll
                for (int r = 0; r < 4; ++r) {
                    float ex = sv[pb][s][r] - mnew;
                    float p = (ex < -80.f) ? 0.f : __expf(ex);
                    rs += p;
                    pk[pb][s * 4 + r] = __builtin_bit_cast(unsigned short, __float2bfloat16(p));
                }
        rs += __shfl_xor(rs, 16, 64);
        rs += __shfl_xor(rs, 32, 64);
        lrun = lrun * alpha + rs;
        mrun = mnew;
#pragma unroll
        for (int t = 0; t < 4; ++t) {
            oaccT[t][0] *= alpha; oaccT[t][1] *= alpha;
            oaccT[t][2] *= alpha; oaccT[t][3] *= alpha;
        }

        // O^T += V^T P^T : A = V^T frag from LDS, B = P^T from registers (layout match by construction)
#pragma unroll
        for (int pb = 0; pb < 2; ++pb) {
            union { unsigned short u[8]; bf16x8 v; } pu;
#pragma unroll
            for (int e = 0; e < 8; ++e) pu.u[e] = pk[pb][e];
            bf16x8 pf = pu.v;
#pragma unroll
            for (int t = 0; t < 4; ++t) {
                bf16x8 vf = ld_frag(&Vs[buf][(t * 16 + l15) * KS + pb * 32 + l4 * 8]);
                oaccT[t] = __builtin_amdgcn_mfma_f32_16x16x32_bf16(vf, pf, oaccT[t], 0, 0, 0);
            }
        }

        if (kt < 32) {
            int ob = buf ^ 1;
#pragma unroll
            for (int rr = 0; rr < 2; ++rr) {
                *(uint4*)&Ks[ob][krow[rr] * KS + sseg[rr] * 8] = kr[rr];
                *(uint4*)&Vs[ob][srow[rr] * KS + sseg[rr] * 8] = vr[rr];
            }
        }
        __syncthreads();
    }

    if (qrow < SEQ1) {
        float rl = (lrun > 0.f) ? 1.f / lrun : 0.f;
        bf16* orow = O + ((size_t)b * SEQ1 + qrow) * DIMC + h * 64;
#pragma unroll
        for (int t = 0; t < 4; ++t) {
            union { unsigned short u[4]; uint2 v; } ou;
#pragma unroll
            for (int r = 0; r < 4; ++r)
                ou.u[r] = __builtin_bit_cast(unsigned short, __float2bfloat16(oaccT[t][r] * rl));
            *(uint2*)&orow[t * 16 + l4 * 4] = ou.v;
        }
    }
}

// ---------------- fused final LN + head (cls row only), fp32 ----------------
__global__ __launch_bounds__(256) void head_kernel(const float* __restrict__ X,
                            const float* __restrict__ g, const float* __restrict__ bb,
                            const float* __restrict__ hw, const float* __restrict__ hb,
                            float* __restrict__ out) {
    int b = blockIdx.x, t = threadIdx.x;
    const float* xr = X + (size_t)b * SEQ1 * DIMC;
    float v0 = xr[t], v1 = xr[t + 256];
    __shared__ float red[256];
    red[t] = v0 + v1;
    __syncthreads();
    for (int w = 128; w > 0; w >>= 1) { if (t < w) red[t] += red[t + w]; __syncthreads(); }
    float mean = red[0] * (1.f / 512.f);
    __syncthreads();
    float d0 = v0 - mean, d1 = v1 - mean;
    red[t] = d0 * d0 + d1 * d1;
    __syncthreads();
    for (int w = 128; w > 0; w >>= 1) { if (t < w) red[t] += red[t + w]; __syncthreads(); }
    float rinv = rsqrtf(red[0] * (1.f / 512.f) + 1e-5f);
    __syncthreads();
    float xn0 = d0 * rinv * g[t] + bb[t];
    float xn1 = d1 * rinv * g[t + 256] + bb[t + 256];
    float p0 = xn0 * hw[t * 2]     + xn1 * hw[(t + 256) * 2];
    float p1 = xn0 * hw[t * 2 + 1] + xn1 * hw[(t + 256) * 2 + 1];
    __shared__ float r0[256], r1[256];
    r0[t] = p0; r1[t] = p1;
    __syncthreads();
    for (int w = 128; w > 0; w >>= 1) { if (t < w) { r0[t] += r0[t + w]; r1[t] += r1[t + w]; } __syncthreads(); }
    if (t == 0) {
        out[b * 2 + 0] = r0[0] + hb[0];
        out[b * 2 + 1] = r1[0] + hb[1];
    }
}

extern "C" void kernel_launch(void* const* d_in, const int* in_sizes, int n_in,
                              void* d_out, int out_size, void* d_ws, size_t ws_size,
                              hipStream_t stream) {
    const float* x      = (const float*)d_in[0];
    const int*   lens   = (const int*)d_in[1];
    const float* cls    = (const float*)d_in[2];
    const float* fc_w   = (const float*)d_in[3];
    const float* fc_b   = (const float*)d_in[4];
    const float* ln1_g  = (const float*)d_in[5];
    const float* ln1_b  = (const float*)d_in[6];
    const float* qkv_w  = (const float*)d_in[7];
    const float* out_w  = (const float*)d_in[8];
    const float* out_b  = (const float*)d_in[9];
    const float* ln2_g  = (const float*)d_in[10];
    const float* ln2_b  = (const float*)d_in[11];
    const float* ff1_w  = (const float*)d_in[12];
    const float* ff1_b  = (const float*)d_in[13];
    const float* ff2_w  = (const float*)d_in[14];
    const float* ff2_b  = (const float*)d_in[15];
    const float* lnf_g  = (const float*)d_in[16];
    const float* lnf_b  = (const float*)d_in[17];
    const float* head_w = (const float*)d_in[18];
    const float* head_b = (const float*)d_in[19];
    float* out = (float*)d_out;

    char* w = (char*)d_ws;
    float* X    = (float*)w;  w += (size_t)ROWS * DIMC * 4;
    bf16*  XNh  = (bf16*)w;   w += (size_t)ROWS * DIMC * 2;
    bf16*  QKVh = (bf16*)w;   w += (size_t)ROWS * 1536 * 2;
    bf16*  Obh  = (bf16*)w;   w += (size_t)ROWS * DIMC * 2;
    bf16*  xbf  = (bf16*)w;   w += (size_t)BATCH * SEQ * DIN * 2;
    bf16*  VT   = xbf;        // alias: xbf dead after stem gemm
    bf16*  fc_wt  = (bf16*)w;
    bf16*  qkv_wt = fc_wt  + (size_t)DIN * DIMC;
    bf16*  out_wt = qkv_wt + (size_t)2 * DIMC * 1536;
    bf16*  ff1_wt = out_wt + (size_t)2 * DIMC * DIMC;
    bf16*  ff2_wt = ff1_wt + (size_t)2 * DIMC * DIMC;
    bf16*  Hbh  = Obh;

    dim3 blk(256);
    dim3 tb(32, 8);

    cast_kernel<<<dim3((BATCH * SEQ * DIN / 4 + 255) / 256), blk, 0, stream>>>(
        x, xbf, BATCH * SEQ * DIN / 4);

    wt_transpose_kernel<<<dim3(16, 24, 1), tb, 0, stream>>>(fc_w,  fc_wt,  DIN,  DIMC, (long)DIN * DIMC);
    wt_transpose_kernel<<<dim3(48, 16, 2), tb, 0, stream>>>(qkv_w, qkv_wt, DIMC, 1536, (long)DIMC * 1536);
    wt_transpose_kernel<<<dim3(16, 16, 2), tb, 0, stream>>>(out_w, out_wt, DIMC, DIMC, (long)DIMC * DIMC);
    wt_transpose_kernel<<<dim3(16, 16, 2), tb, 0, stream>>>(ff1_w, ff1_wt, DIMC, DIMC, (long)DIMC * DIMC);
    wt_transpose_kernel<<<dim3(16, 16, 2), tb, 0, stream>>>(ff2_w, ff2_wt, DIMC, DIMC, (long)DIMC * DIMC);

    gemm_bt<true, false, true, false><<<dim3(4, 64), blk, 0, stream>>>(
        xbf, fc_wt, fc_b, nullptr, X, nullptr, BATCH * SEQ, DIMC, DIN);
    cls_fill_kernel<<<dim3(BATCH), blk, 0, stream>>>(cls, X);

    for (int l = 0; l < DEPTH; ++l) {
        ln_kernel<<<dim3(ROWS), blk, 0, stream>>>(X, XNh, ln1_g + l * DIMC, ln1_b + l * DIMC);
        gemm_bt<false, false, false, true><<<dim3(12, 65), blk, 0, stream>>>(
            XNh, qkv_wt + (size_t)l * DIMC * 1536, nullptr, nullptr, nullptr, QKVh, ROWS, 1536, DIMC);
        vt_transpose_kernel<<<dim3(2, 66, 32), tb, 0, stream>>>(QKVh, VT);
        attn_kernel<<<dim3(33, NHEAD, BATCH), blk, 0, stream>>>(QKVh, VT, lens, Obh);
        gemm_bt<false, true, false, false><<<dim3(4, 65), blk, 0, stream>>>(
            Obh, out_wt + (size_t)l * DIMC * DIMC, out_b + l * DIMC, X, X, nullptr, ROWS, DIMC, DIMC);
        ln_kernel<<<dim3(ROWS), blk, 0, stream>>>(X, XNh, ln2_g + l * DIMC, ln2_b + l * DIMC);
        gemm_bt<true, false, false, true><<<dim3(4, 65), blk, 0, stream>>>(
            XNh, ff1_wt + (size_t)l * DIMC * DIMC, ff1_b + l * DIMC, nullptr, nullptr, Hbh, ROWS, DIMC, DIMC);
        gemm_bt<false, true, false, false><<<dim3(4, 65), blk, 0, stream>>>(
            Hbh, ff2_wt + (size_t)l * DIMC * DIMC, ff2_b + l * DIMC, X, X, nullptr, ROWS, DIMC, DIMC);
    }
    head_kernel<<<dim3(BATCH), blk, 0, stream>>>(X, lnf_g, lnf_b, head_w, head_b, out);
}